// Round 1
// baseline (200.091 us; speedup 1.0000x reference)
//
#include <hip/hip_runtime.h>
#include <hip/hip_fp16.h>
#include <cmath>

// Fixed problem shape: x = (8, 3, 1024, 1024) fp32.
#define HH   1024
#define WW   1024
#define HW   (HH * WW)

#define SW    64      // tile width  (output cols per block)
#define TH    128     // tile height (output rows per block)
#define T31R  158     // TH + 30
#define T7R   134     // TH + 6
#define SROWS 16      // luma stage rows per iteration
#define SPIT  96      // stage row width in halves = SW + 32

// ---- compile-time gaussian weights (matches np: exp(-d^2/(2 sigma^2)) / sum) ----
constexpr double cexp(double v) {
    double term = 1.0, sum = 1.0;
    for (int i = 1; i < 64; ++i) { term *= v / (double)i; sum += term; }
    return sum;
}
struct GW { float g31[31]; float g7[7]; };
constexpr GW make_gw() {
    GW r{};
    double t31[31]; double s31 = 0.0;
    for (int i = 0; i < 31; ++i) { double d = (double)(i - 15); t31[i] = cexp(-d * d / 128.0); s31 += t31[i]; }
    for (int i = 0; i < 31; ++i) r.g31[i] = (float)(t31[i] / s31);
    double t7[7]; double s7 = 0.0;
    for (int i = 0; i < 7; ++i) { double d = (double)(i - 3); t7[i] = cexp(-d * d / 4.5); s7 += t7[i]; }
    for (int i = 0; i < 7; ++i) r.g7[i] = (float)(t7[i] / s7);
    return r;
}
__constant__ GW GWC = make_gw();

// ---------------------------------------------------------------------------
// Tile kernel: block = 256 threads, output tile 128 rows x 64 cols.
// LDS = 20224 (t31 fp16) + 17152 (t7 fp16) + 3072 (fp16 luma stage)
//     = 40448 B  ->  4 blocks/CU (163840/40448), grid 1024 = exactly 4/CU,
//     zero tail. VGPR target <=128 for 16 waves/CU.
// Phase 1 (10 iters): stage 16 luma rows (+/-16 col halo, fp16), each thread
//   h-blurs 4 px of one row (31-tap & 7-tap) -> fp16 LDS tiles.
// Phase 2: vertical conv from LDS, scalar column per thread (2 row-group
//   tasks), combine with L2-hot x re-read, store.
// Zero padding outside the image matches jax conv exactly.
// ---------------------------------------------------------------------------
__global__ __launch_bounds__(256, 4)
void fused_tile(const float* __restrict__ x,
                const float* __restrict__ clar,
                const float* __restrict__ tex,
                float* __restrict__ out) {
    __shared__ __align__(16) __half t31s [T31R][SW];
    __shared__ __align__(16) __half t7s  [T7R][SW];
    __shared__ __align__(16) __half stage[SROWS][SPIT];

    // XCD swizzle: all 8 bands of one (img,strip) column on one XCD so the
    // 30-row luma halo overlap between vertical neighbors reuses its L2.
    const int id    = blockIdx.x;
    const int xcd   = id & 7;
    const int k     = id >> 3;             // 0..127
    const int combo = xcd * 16 + (k & 15); // 0..127 = img*16 + strip
    const int band  = k >> 4;              // 0..7
    const int img   = combo >> 4;
    const int strip = combo & 15;

    const int y0 = band * TH;
    const int x0 = strip * SW;
    const int t  = threadIdx.x;

    const float* xb = x   + (size_t)img * 3 * HW;
    float*       ob = out + (size_t)img * 3 * HW;

    // ---------------- phase 1: horizontal blurs into LDS tiles ----------------
    for (int it = 0; it < 10; ++it) {
        const int gbase = it * SROWS;

        // stage 16 luma rows: 16 rows x 24 four-px units = 384 units
        #pragma unroll
        for (int s = 0; s < 2; ++s) {
            const int u = t + 256 * s;
            if (u < 384) {
                const int r   = u / 24;
                const int c8  = u - 24 * r;       // four-px unit within row
                const int tr  = gbase + r;
                const int y   = y0 - 15 + tr;
                const int col = x0 - 16 + 4 * c8; // 4-aligned: float4 fully in/out
                float4 L = make_float4(0.f, 0.f, 0.f, 0.f);
                if (tr < T31R && (unsigned)y < (unsigned)HH && (unsigned)col < (unsigned)WW) {
                    const float* xr = xb + (size_t)y * WW + col;
                    const float4 R  = *(const float4*)(xr);
                    const float4 G  = *(const float4*)(xr + HW);
                    const float4 Bc = *(const float4*)(xr + 2 * HW);
                    L.x = fmaf(0.2126f, R.x, fmaf(0.7152f, G.x, 0.0722f * Bc.x));
                    L.y = fmaf(0.2126f, R.y, fmaf(0.7152f, G.y, 0.0722f * Bc.y));
                    L.z = fmaf(0.2126f, R.z, fmaf(0.7152f, G.z, 0.0722f * Bc.z));
                    L.w = fmaf(0.2126f, R.w, fmaf(0.7152f, G.w, 0.0722f * Bc.w));
                }
                union { float2 f; __half2 h[2]; } W;
                W.h[0] = __floats2half2_rn(L.x, L.y);
                W.h[1] = __floats2half2_rn(L.z, L.w);
                *(float2*)&stage[r][4 * c8] = W.f;   // 8-byte aligned
            }
        }
        __syncthreads();

        // h-blur: thread -> row (t>>4), 4 px at cols 4*(t&15)
        {
            const int lr = t >> 4;
            const int c  = t & 15;
            const int tr = gbase + lr;
            if (tr < T31R) {
                float win[36];
                #pragma unroll
                for (int q = 0; q < 9; ++q) {
                    union { float2 f; __half2 h[2]; } U;
                    U.f = *(const float2*)&stage[lr][4 * c + 4 * q];  // 8B aligned
                    const float2 a = __half22float2(U.h[0]);
                    const float2 b = __half22float2(U.h[1]);
                    win[4 * q]     = a.x; win[4 * q + 1] = a.y;
                    win[4 * q + 2] = b.x; win[4 * q + 3] = b.y;
                }
                float o[4] = {0.f, 0.f, 0.f, 0.f};
                float p[4] = {0.f, 0.f, 0.f, 0.f};
                #pragma unroll
                for (int s = 0; s < 31; ++s) {
                    const float g = GWC.g31[s];
                    o[0] = fmaf(g, win[1 + s], o[0]);
                    o[1] = fmaf(g, win[2 + s], o[1]);
                    o[2] = fmaf(g, win[3 + s], o[2]);
                    o[3] = fmaf(g, win[4 + s], o[3]);
                }
                #pragma unroll
                for (int s = 0; s < 7; ++s) {
                    const float g = GWC.g7[s];
                    p[0] = fmaf(g, win[13 + s], p[0]);
                    p[1] = fmaf(g, win[14 + s], p[1]);
                    p[2] = fmaf(g, win[15 + s], p[2]);
                    p[3] = fmaf(g, win[16 + s], p[3]);
                }
                union { float2 f; __half2 h[2]; } W;
                W.h[0] = __floats2half2_rn(o[0], o[1]);
                W.h[1] = __floats2half2_rn(o[2], o[3]);
                *(float2*)&t31s[tr][4 * c] = W.f;
                if (tr >= 12 && tr < 12 + T7R) {
                    union { float2 f; __half2 h[2]; } V;
                    V.h[0] = __floats2half2_rn(p[0], p[1]);
                    V.h[1] = __floats2half2_rn(p[2], p[3]);
                    *(float2*)&t7s[tr - 12][4 * c] = V.f;
                }
            }
        }
        __syncthreads();
    }

    // ---------------- phase 2: vertical blurs + combine ----------------
    const float ca = tanhf(clar[0]) * 0.5f;
    const float ta = tanhf(tex[0]) * 0.3f;

    const int c = t & 63;                 // column within tile
    #pragma unroll
    for (int s = 0; s < 2; ++s) {
        const int rg = (t >> 6) + 4 * s;  // row group 0..7
        const int r0 = rg * 16;           // output rows r0..r0+15 (tile-rel)

        float w31[31];
        #pragma unroll
        for (int q = 0; q < 30; ++q) w31[q] = __half2float(t31s[r0 + q][c]);
        float w7[7];
        #pragma unroll
        for (int q = 0; q < 6; ++q) w7[q] = __half2float(t7s[r0 + q][c]);

        #pragma unroll
        for (int j = 0; j < 16; ++j) {
            w31[(30 + j) % 31] = __half2float(t31s[r0 + 30 + j][c]);
            w7 [(6 + j) % 7]   = __half2float(t7s [r0 + 6 + j][c]);

            float a31 = 0.f;
            #pragma unroll
            for (int q = 0; q < 31; ++q)
                a31 = fmaf(GWC.g31[q], w31[(j + q) % 31], a31);
            float a7 = 0.f;
            #pragma unroll
            for (int q = 0; q < 7; ++q)
                a7 = fmaf(GWC.g7[q], w7[(j + q) % 7], a7);

            const int y = y0 + r0 + j;
            const float* px = xb + (size_t)y * WW + x0 + c;
            const float R  = px[0];
            const float G  = px[HW];
            const float Bc = px[2 * HW];

            const float L     = fmaf(0.2126f, R, fmaf(0.7152f, G, 0.0722f * Bc));
            const float le    = L + ca * (L - a31) + ta * (L - a7);
            const float ratio = (le + 1e-6f) / (L + 1e-6f);

            float* qo = ob + (size_t)y * WW + x0 + c;
            qo[0]      = fminf(fmaxf(R  * ratio, 0.f), 1.f);
            qo[HW]     = fminf(fmaxf(G  * ratio, 0.f), 1.f);
            qo[2 * HW] = fminf(fmaxf(Bc * ratio, 0.f), 1.f);
        }
    }
}

extern "C" void kernel_launch(void* const* d_in, const int* in_sizes, int n_in,
                              void* d_out, int out_size, void* d_ws, size_t ws_size,
                              hipStream_t stream) {
    const float* x    = (const float*)d_in[0];
    const float* clar = (const float*)d_in[1];
    const float* tex  = (const float*)d_in[2];
    float* out = (float*)d_out;

    dim3 grid(8 * 16 * 8);   // 1024 blocks: 8 imgs x 16 strips x 8 bands = 4/CU exact
    dim3 block(256);
    hipLaunchKernelGGL(fused_tile, grid, block, 0, stream, x, clar, tex, out);
}

// Round 2
// 197.246 us; speedup vs baseline: 1.0144x; 1.0144x over previous
//
#include <hip/hip_runtime.h>
#include <hip/hip_fp16.h>
#include <cmath>

// Fixed problem shape: x = (8, 3, 1024, 1024) fp32.
#define HH   1024
#define WW   1024
#define HW   (HH * WW)

#define SW    64      // tile width  (output cols per block)
#define TH    128     // tile height (output rows per block)
#define T31R  158     // TH + 30
#define T7R   134     // TH + 6
#define SROWS 16      // luma stage rows per iteration
#define SPIT  96      // stage row width in halves = SW + 32

// ---- compile-time gaussian weights (matches np: exp(-d^2/(2 sigma^2)) / sum) ----
constexpr double cexp(double v) {
    double term = 1.0, sum = 1.0;
    for (int i = 1; i < 64; ++i) { term *= v / (double)i; sum += term; }
    return sum;
}
struct GW { float g31[31]; float g7[7]; };
constexpr GW make_gw() {
    GW r{};
    double t31[31]; double s31 = 0.0;
    for (int i = 0; i < 31; ++i) { double d = (double)(i - 15); t31[i] = cexp(-d * d / 128.0); s31 += t31[i]; }
    for (int i = 0; i < 31; ++i) r.g31[i] = (float)(t31[i] / s31);
    double t7[7]; double s7 = 0.0;
    for (int i = 0; i < 7; ++i) { double d = (double)(i - 3); t7[i] = cexp(-d * d / 4.5); s7 += t7[i]; }
    for (int i = 0; i < 7; ++i) r.g7[i] = (float)(t7[i] / s7);
    return r;
}
__constant__ GW GWC = make_gw();

// ---------------------------------------------------------------------------
// V2 changes vs 200µs baseline (dispatch ~82µs, VALUBusy 34%, HBM 32%,
// occupancy 37.6% -> latency-bound, not pipe-bound):
//  1. Phase 1 software-pipelined (T14 issue-early/write-late): next
//     iteration's stage float4 loads are issued into registers right after
//     the first barrier, so h-blur compute + barrier hide HBM latency.
//  2. Phase 2 vectorized 2 cols/thread: half2 LDS reads, fp32 float2 math,
//     float2 global load/store, depth-1 register prefetch of the L2-hot
//     x re-read. Halves phase-2 LDS/VMEM instruction count.
// LDS unchanged: 40448 B -> 4 blocks/CU, grid 1024 = exactly 4/CU.
// ---------------------------------------------------------------------------
__global__ __launch_bounds__(256, 4)
void fused_tile(const float* __restrict__ x,
                const float* __restrict__ clar,
                const float* __restrict__ tex,
                float* __restrict__ out) {
    __shared__ __align__(16) __half t31s [T31R][SW];
    __shared__ __align__(16) __half t7s  [T7R][SW];
    __shared__ __align__(16) __half stage[SROWS][SPIT];

    // XCD swizzle: all 8 bands of one (img,strip) column on one XCD so the
    // 30-row luma halo overlap between vertical neighbors reuses its L2.
    const int id    = blockIdx.x;
    const int xcd   = id & 7;
    const int k     = id >> 3;             // 0..127
    const int combo = xcd * 16 + (k & 15); // 0..127 = img*16 + strip
    const int band  = k >> 4;              // 0..7
    const int img   = combo >> 4;
    const int strip = combo & 15;

    const int y0 = band * TH;
    const int x0 = strip * SW;
    const int t  = threadIdx.x;

    const float* xb = x   + (size_t)img * 3 * HW;
    float*       ob = out + (size_t)img * 3 * HW;

    // ---- staging geometry: 384 four-px units over 256 threads (unit0 = t,
    // unit1 = t+256 for t<128), fixed (row, col) per thread across iters ----
    const int r0u = t / 24;
    const int c80 = t - 24 * r0u;
    const int u1  = t + 256;
    const int r1u = u1 / 24;
    const int c81 = u1 - 24 * r1u;
    const bool has1 = (t < 128);
    const int col0 = x0 - 16 + 4 * c80;
    const int col1 = x0 - 16 + 4 * c81;
    const bool c0ok = (unsigned)col0 < (unsigned)WW;
    const bool c1ok = (unsigned)col1 < (unsigned)WW;

    float4 R0, G0, B0, R1, G1, B1;

    // issue the global loads for iteration `it` into registers (no waits here)
    auto issue = [&](int it) {
        const int gbase = it * SROWS;
        {
            const int tr = gbase + r0u;
            const int y  = y0 - 15 + tr;
            if (tr < T31R && (unsigned)y < (unsigned)HH && c0ok) {
                const float* xr = xb + (size_t)y * WW + col0;
                R0 = *(const float4*)(xr);
                G0 = *(const float4*)(xr + HW);
                B0 = *(const float4*)(xr + 2 * HW);
            } else {
                R0 = make_float4(0.f, 0.f, 0.f, 0.f); G0 = R0; B0 = R0;
            }
        }
        if (has1) {
            const int tr = gbase + r1u;
            const int y  = y0 - 15 + tr;
            if (tr < T31R && (unsigned)y < (unsigned)HH && c1ok) {
                const float* xr = xb + (size_t)y * WW + col1;
                R1 = *(const float4*)(xr);
                G1 = *(const float4*)(xr + HW);
                B1 = *(const float4*)(xr + 2 * HW);
            } else {
                R1 = make_float4(0.f, 0.f, 0.f, 0.f); G1 = R1; B1 = R1;
            }
        }
    };

    issue(0);   // prologue

    // ---------------- phase 1: horizontal blurs into LDS tiles ----------------
    for (int it = 0; it < 10; ++it) {
        // consume prefetched regs -> fp16 luma stage (waitcnt lands here,
        // latency was covered by previous iteration's h-blur + barrier)
        {
            union { float2 f; __half2 h[2]; } W;
            W.h[0] = __floats2half2_rn(fmaf(0.2126f, R0.x, fmaf(0.7152f, G0.x, 0.0722f * B0.x)),
                                       fmaf(0.2126f, R0.y, fmaf(0.7152f, G0.y, 0.0722f * B0.y)));
            W.h[1] = __floats2half2_rn(fmaf(0.2126f, R0.z, fmaf(0.7152f, G0.z, 0.0722f * B0.z)),
                                       fmaf(0.2126f, R0.w, fmaf(0.7152f, G0.w, 0.0722f * B0.w)));
            *(float2*)&stage[r0u][4 * c80] = W.f;   // 8-byte aligned
            if (has1) {
                union { float2 f; __half2 h[2]; } V;
                V.h[0] = __floats2half2_rn(fmaf(0.2126f, R1.x, fmaf(0.7152f, G1.x, 0.0722f * B1.x)),
                                           fmaf(0.2126f, R1.y, fmaf(0.7152f, G1.y, 0.0722f * B1.y)));
                V.h[1] = __floats2half2_rn(fmaf(0.2126f, R1.z, fmaf(0.7152f, G1.z, 0.0722f * B1.z)),
                                           fmaf(0.2126f, R1.w, fmaf(0.7152f, G1.w, 0.0722f * B1.w)));
                *(float2*)&stage[r1u][4 * c81] = V.f;
            }
        }
        __syncthreads();

        // issue next iteration's loads NOW: h-blur below + loop barrier hide
        // the HBM latency. Targets registers only -> no LDS hazard.
        if (it + 1 < 10) issue(it + 1);

        // h-blur: thread -> row (t>>4), 4 px at cols 4*(t&15)
        {
            const int gbase = it * SROWS;
            const int lr = t >> 4;
            const int c  = t & 15;
            const int tr = gbase + lr;
            if (tr < T31R) {
                float win[36];
                #pragma unroll
                for (int q = 0; q < 9; ++q) {
                    union { float2 f; __half2 h[2]; } U;
                    U.f = *(const float2*)&stage[lr][4 * c + 4 * q];  // 8B aligned
                    const float2 a = __half22float2(U.h[0]);
                    const float2 b = __half22float2(U.h[1]);
                    win[4 * q]     = a.x; win[4 * q + 1] = a.y;
                    win[4 * q + 2] = b.x; win[4 * q + 3] = b.y;
                }
                float o[4] = {0.f, 0.f, 0.f, 0.f};
                float p[4] = {0.f, 0.f, 0.f, 0.f};
                #pragma unroll
                for (int s = 0; s < 31; ++s) {
                    const float g = GWC.g31[s];
                    o[0] = fmaf(g, win[1 + s], o[0]);
                    o[1] = fmaf(g, win[2 + s], o[1]);
                    o[2] = fmaf(g, win[3 + s], o[2]);
                    o[3] = fmaf(g, win[4 + s], o[3]);
                }
                #pragma unroll
                for (int s = 0; s < 7; ++s) {
                    const float g = GWC.g7[s];
                    p[0] = fmaf(g, win[13 + s], p[0]);
                    p[1] = fmaf(g, win[14 + s], p[1]);
                    p[2] = fmaf(g, win[15 + s], p[2]);
                    p[3] = fmaf(g, win[16 + s], p[3]);
                }
                union { float2 f; __half2 h[2]; } W;
                W.h[0] = __floats2half2_rn(o[0], o[1]);
                W.h[1] = __floats2half2_rn(o[2], o[3]);
                *(float2*)&t31s[tr][4 * c] = W.f;
                if (tr >= 12 && tr < 12 + T7R) {
                    union { float2 f; __half2 h[2]; } V;
                    V.h[0] = __floats2half2_rn(p[0], p[1]);
                    V.h[1] = __floats2half2_rn(p[2], p[3]);
                    *(float2*)&t7s[tr - 12][4 * c] = V.f;
                }
            }
        }
        __syncthreads();
    }

    // ---------------- phase 2: vertical blurs + combine, 2 cols/thread ----------------
    const float ca = tanhf(clar[0]) * 0.5f;
    const float ta = tanhf(tex[0]) * 0.3f;

    const int cc = (t & 31) * 2;          // even column within tile
    const int rg = t >> 5;                // row group 0..7
    const int r0 = rg * 16;               // output rows r0..r0+15 (tile-rel)

    float2 w31[31];
    #pragma unroll
    for (int q = 0; q < 30; ++q)
        w31[q] = __half22float2(*(const __half2*)&t31s[r0 + q][cc]);
    float2 w7[7];
    #pragma unroll
    for (int q = 0; q < 6; ++q)
        w7[q] = __half22float2(*(const __half2*)&t7s[r0 + q][cc]);

    // prefetch x row j=0 (L2-hot re-read)
    {
    const float* p0 = xb + (size_t)(y0 + r0) * WW + x0 + cc;
    float2 R  = *(const float2*)(p0);
    float2 G  = *(const float2*)(p0 + HW);
    float2 Bc = *(const float2*)(p0 + 2 * HW);

    #pragma unroll
    for (int j = 0; j < 16; ++j) {
        w31[(30 + j) % 31] = __half22float2(*(const __half2*)&t31s[r0 + 30 + j][cc]);
        w7 [(6 + j) % 7]   = __half22float2(*(const __half2*)&t7s [r0 + 6 + j][cc]);

        // issue next row's x loads before the conv chain (latency cover)
        float2 Rn, Gn, Bn;
        if (j < 15) {
            const float* pn = xb + (size_t)(y0 + r0 + j + 1) * WW + x0 + cc;
            Rn = *(const float2*)(pn);
            Gn = *(const float2*)(pn + HW);
            Bn = *(const float2*)(pn + 2 * HW);
        }

        float2 a31 = make_float2(0.f, 0.f);
        #pragma unroll
        for (int q = 0; q < 31; ++q) {
            const float g = GWC.g31[q];
            const float2 w = w31[(j + q) % 31];
            a31.x = fmaf(g, w.x, a31.x);
            a31.y = fmaf(g, w.y, a31.y);
        }
        float2 a7 = make_float2(0.f, 0.f);
        #pragma unroll
        for (int q = 0; q < 7; ++q) {
            const float g = GWC.g7[q];
            const float2 w = w7[(j + q) % 7];
            a7.x = fmaf(g, w.x, a7.x);
            a7.y = fmaf(g, w.y, a7.y);
        }

        const int y = y0 + r0 + j;
        float* qo = ob + (size_t)y * WW + x0 + cc;

        const float Lx = fmaf(0.2126f, R.x, fmaf(0.7152f, G.x, 0.0722f * Bc.x));
        const float Ly = fmaf(0.2126f, R.y, fmaf(0.7152f, G.y, 0.0722f * Bc.y));
        const float lex = Lx + ca * (Lx - a31.x) + ta * (Lx - a7.x);
        const float ley = Ly + ca * (Ly - a31.y) + ta * (Ly - a7.y);
        const float rx = (lex + 1e-6f) / (Lx + 1e-6f);
        const float ry = (ley + 1e-6f) / (Ly + 1e-6f);

        float2 o0, o1, o2;
        o0.x = fminf(fmaxf(R.x  * rx, 0.f), 1.f);  o0.y = fminf(fmaxf(R.y  * ry, 0.f), 1.f);
        o1.x = fminf(fmaxf(G.x  * rx, 0.f), 1.f);  o1.y = fminf(fmaxf(G.y  * ry, 0.f), 1.f);
        o2.x = fminf(fmaxf(Bc.x * rx, 0.f), 1.f);  o2.y = fminf(fmaxf(Bc.y * ry, 0.f), 1.f);
        *(float2*)(qo)          = o0;
        *(float2*)(qo + HW)     = o1;
        *(float2*)(qo + 2 * HW) = o2;

        if (j < 15) { R = Rn; G = Gn; Bc = Bn; }
    }
    }
}

extern "C" void kernel_launch(void* const* d_in, const int* in_sizes, int n_in,
                              void* d_out, int out_size, void* d_ws, size_t ws_size,
                              hipStream_t stream) {
    const float* x    = (const float*)d_in[0];
    const float* clar = (const float*)d_in[1];
    const float* tex  = (const float*)d_in[2];
    float* out = (float*)d_out;

    dim3 grid(8 * 16 * 8);   // 1024 blocks: 8 imgs x 16 strips x 8 bands = 4/CU exact
    dim3 block(256);
    hipLaunchKernelGGL(fused_tile, grid, block, 0, stream, x, clar, tex, out);
}